// Round 5
// baseline (267.019 us; speedup 1.0000x reference)
//
#include <hip/hip_runtime.h>
#include <hip/hip_bf16.h>

// Problem constants (from reference)
#define GG   8
#define NN   10000
#define EE   160000       // = 625 * 256 exactly
#define DIN  300
#define KP1  320          // DIN padded to mult of 32
#define DH   256
#define DOUT 128
#define MTOT 80000        // G*N rows
#define LN_EPS 1e-5f

typedef short bf16x8 __attribute__((ext_vector_type(8)));
typedef float f32x4  __attribute__((ext_vector_type(4)));
typedef ushort u16x8 __attribute__((ext_vector_type(8)));

__device__ inline float bf2f(ushort u) {
    union { unsigned int i; float f; } x;
    x.i = ((unsigned int)u) << 16;
    return x.f;
}
__device__ inline ushort f2b(float f) {
    union { float f; unsigned int u; } x;
    x.f = f;
    unsigned int u = x.u;
    return (ushort)((u + 0x7fffu + ((u >> 16) & 1u)) >> 16);  // RNE (finite values)
}
__device__ inline short bcvt(float f) {
    __hip_bfloat16 h = __float2bfloat16(f);   // RNE; compiler emits v_cvt
    return *reinterpret_cast<short*>(&h);
}

// ---------------------------------------------------------------------------
// k_util: zero cnt + cast W1 -> w1t [256][320] + cast W2 -> w2t [128][256]
// ---------------------------------------------------------------------------
__global__ __launch_bounds__(256) void k_util(const float* __restrict__ W1,
                                              const float* __restrict__ W2,
                                              ushort* __restrict__ w1t,
                                              ushort* __restrict__ w2t,
                                              int* __restrict__ cnt) {
    int i = blockIdx.x * blockDim.x + threadIdx.x;
    if (i < GG * NN) cnt[i] = 0;
    if (i < DH * KP1) {
        int n = i / KP1, k = i % KP1;
        w1t[i] = (k < DIN) ? f2b(W1[(size_t)k * DH + n]) : 0;
    }
    if (i < DOUT * DH) {
        int n = i / DH, k = i % DH;
        w2t[i] = f2b(W2[(size_t)k * DOUT + n]);
    }
}

// ---------------------------------------------------------------------------
// CSR build kernels
// ---------------------------------------------------------------------------
__global__ __launch_bounds__(256) void k_count(const int* __restrict__ ei,
                                               int* __restrict__ cnt,
                                               int* __restrict__ slot) {
    int bid = blockIdx.x;
    int g = bid & 7;
    int e = (bid >> 3) * 256 + threadIdx.x;       // e < EE exactly
    int dst = ei[(size_t)g * 2 * EE + EE + e];
    slot[(size_t)g * EE + e] = atomicAdd(&cnt[g * NN + dst], 1);
}

__global__ void k_scan(const int* __restrict__ cnt, int* __restrict__ rowptr,
                       float* __restrict__ dinv) {
    int g = blockIdx.x;
    int t = threadIdx.x;                // 256 threads
    const int per = (NN + 255) / 256;   // 40
    __shared__ int sums[256];
    __shared__ int offs[257];
    int base = t * per;
    int s = 0;
    for (int i = 0; i < per; i++) {
        int n = base + i;
        if (n < NN) s += cnt[g * NN + n];
    }
    sums[t] = s;
    __syncthreads();
    if (t == 0) {
        int acc = 0;
        for (int i = 0; i < 256; i++) { offs[i] = acc; acc += sums[i]; }
        offs[256] = acc;
    }
    __syncthreads();
    int run = offs[t];
    for (int i = 0; i < per; i++) {
        int n = base + i;
        if (n < NN) {
            int c = cnt[g * NN + n];
            rowptr[g * (NN + 1) + n] = run;
            dinv[g * NN + n] = 1.0f / sqrtf(1.0f + (float)c);
            run += c;
        }
    }
    if (t == 255) rowptr[g * (NN + 1) + NN] = offs[256];
}

__global__ __launch_bounds__(256) void k_fill(const int* __restrict__ ei,
                                              const int* __restrict__ rowptr,
                                              const int* __restrict__ slot,
                                              const float* __restrict__ dinv,
                                              int2* __restrict__ edges) {
    int bid = blockIdx.x;
    int g = bid & 7;
    int e = (bid >> 3) * 256 + threadIdx.x;
    int src = ei[(size_t)g * 2 * EE + e];
    int dst = ei[(size_t)g * 2 * EE + EE + e];
    int pos = rowptr[g * (NN + 1) + dst] + slot[(size_t)g * EE + e];
    float coef = dinv[g * NN + src] * dinv[g * NN + dst];
    int2 rec;
    rec.x = src;
    rec.y = __float_as_int(coef);
    edges[(size_t)g * EE + pos] = rec;
}

// ---------------------------------------------------------------------------
// GEMM1:  C[80000,256] = bf16(x[80000,300]) @ W1   (fused fp32->bf16 cast)
// NEW STRUCTURE for {K tiny, B tiny, M huge}: stage the block's B-quarter in
// LDS ONCE (padded, bank-even), barrier ONCE, then a BARRIER-FREE M-loop:
// each wave owns 32 rows; A fragments load DIRECTLY global->VGPR (16 rows x
// contiguous 32B/lane-pair, coalesced), cvt to bf16 in-register, MFMA against
// B fragments from LDS.  Latency hidden by ILP (40 indep loads/lane in the
// unrolled K chain, no barrier ever drains them) instead of barrier TLP.
// LDS stride 328 ushorts = 164 words == 4 (mod 32): each b128 B-read is
// exactly 8 words/bank -> conflict-free (verified arithmetically).
// K-tail: float4-granular clamp to col 296; cols>=300 hit w1t zero pad.
// M-tail (grid covers 80128): loads row-clamped, stores guarded.
// grid (4 N-quarters, 313 M-blocks), 512 threads = 8 waves x 32 rows.
// ---------------------------------------------------------------------------
__global__ __launch_bounds__(512) void k_gemm1(const float* __restrict__ x,
                                               const ushort* __restrict__ Bt,
                                               ushort* __restrict__ C) {
    __shared__ ushort Bs[64 * 328];     // 42 KB, stride 328 (bank-even)
    const int tid = threadIdx.x;
    const int lane = tid & 63;
    const int w = tid >> 6;             // 0..7
    const int n0 = blockIdx.x * 64;     // col quarter base
    const int fr = lane & 15;
    const int fk = (lane >> 4) * 8;     // 0,8,16,24 (elements)

    // stage B-quarter once: 64 rows x 320 -> padded LDS
    for (int idx = tid; idx < 64 * 40; idx += 512) {
        const int r = idx / 40, c8 = (idx - r * 40) * 8;
        *(u16x8*)&Bs[r * 328 + c8] = *(const u16x8*)&Bt[(size_t)(n0 + r) * KP1 + c8];
    }
    __syncthreads();
    // ------- barrier-free from here on (Bs is read-only) -------

    const int rbase = blockIdx.y * 256 + w * 32;
    const float* xr0 = x + (size_t)min(rbase + fr,      MTOT - 1) * DIN;
    const float* xr1 = x + (size_t)min(rbase + 16 + fr, MTOT - 1) * DIN;

    f32x4 acc[2][4];
#pragma unroll
    for (int g = 0; g < 2; g++)
#pragma unroll
        for (int j = 0; j < 4; j++) acc[g][j] = (f32x4){0.f, 0.f, 0.f, 0.f};

#pragma unroll
    for (int kk = 0; kk < 10; kk++) {
        const int kb = kk * 32 + fk;
        const int c0 = min(kb, DIN - 4);        // float4-granular clamp (296)
        const int c1 = min(kb + 4, DIN - 4);    // slots >=300 meet zero-B
        f32x4 p0 = *(const f32x4*)(xr0 + c0);
        f32x4 q0 = *(const f32x4*)(xr0 + c1);
        f32x4 p1 = *(const f32x4*)(xr1 + c0);
        f32x4 q1 = *(const f32x4*)(xr1 + c1);
        bf16x8 a0, a1;
        a0[0] = bcvt(p0[0]); a0[1] = bcvt(p0[1]); a0[2] = bcvt(p0[2]); a0[3] = bcvt(p0[3]);
        a0[4] = bcvt(q0[0]); a0[5] = bcvt(q0[1]); a0[6] = bcvt(q0[2]); a0[7] = bcvt(q0[3]);
        a1[0] = bcvt(p1[0]); a1[1] = bcvt(p1[1]); a1[2] = bcvt(p1[2]); a1[3] = bcvt(p1[3]);
        a1[4] = bcvt(q1[0]); a1[5] = bcvt(q1[1]); a1[6] = bcvt(q1[2]); a1[7] = bcvt(q1[3]);
        bf16x8 bv[4];
#pragma unroll
        for (int j = 0; j < 4; j++)
            bv[j] = *(const bf16x8*)&Bs[(j * 16 + fr) * 328 + kb];
#pragma unroll
        for (int j = 0; j < 4; j++) {
            acc[0][j] = __builtin_amdgcn_mfma_f32_16x16x32_bf16(a0, bv[j], acc[0][j], 0, 0, 0);
            acc[1][j] = __builtin_amdgcn_mfma_f32_16x16x32_bf16(a1, bv[j], acc[1][j], 0, 0, 0);
        }
    }

    // epilogue: C/D layout col=lane&15, row=(lane>>4)*4+q; M-tail guarded
#pragma unroll
    for (int g = 0; g < 2; g++) {
        const int row0 = rbase + g * 16 + (lane >> 4) * 4;
#pragma unroll
        for (int j = 0; j < 4; j++) {
            const int col = n0 + j * 16 + fr;
#pragma unroll
            for (int q = 0; q < 4; q++) {
                const int row = row0 + q;
                if (row < MTOT)
                    C[(size_t)row * DH + col] = f2b(acc[g][j][q]);
            }
        }
    }
}

// ---------------------------------------------------------------------------
// GEMM2: C[80000,128] = A[80000,256](bf16) @ w2t[128,256]^T
// Same new structure; whole B fits LDS (128 x 264 = 66 KB, bank-even pad).
// grid 313 M-blocks, 512 threads = 8 waves x 32 rows, barrier-free M-loop.
// ---------------------------------------------------------------------------
__global__ __launch_bounds__(512) void k_gemm2(const ushort* __restrict__ A,
                                               const ushort* __restrict__ Bt,
                                               ushort* __restrict__ C) {
    __shared__ ushort Bs[128 * 264];    // 66 KB, stride 264 (bank-even)
    const int tid = threadIdx.x;
    const int lane = tid & 63;
    const int w = tid >> 6;
    const int fr = lane & 15;
    const int fk = (lane >> 4) * 8;

    // stage full B once: 128 rows x 256
    for (int idx = tid; idx < 128 * 32; idx += 512) {
        const int r = idx >> 5, c8 = (idx & 31) * 8;
        *(u16x8*)&Bs[r * 264 + c8] = *(const u16x8*)&Bt[(size_t)r * DH + c8];
    }
    __syncthreads();
    // ------- barrier-free from here on -------

    const int rbase = blockIdx.x * 256 + w * 32;
    const ushort* ar0 = A + (size_t)min(rbase + fr,      MTOT - 1) * DH;
    const ushort* ar1 = A + (size_t)min(rbase + 16 + fr, MTOT - 1) * DH;

    f32x4 acc[2][8];
#pragma unroll
    for (int g = 0; g < 2; g++)
#pragma unroll
        for (int j = 0; j < 8; j++) acc[g][j] = (f32x4){0.f, 0.f, 0.f, 0.f};

#pragma unroll
    for (int kk = 0; kk < 8; kk++) {
        const int kb = kk * 32 + fk;
        bf16x8 a0 = *(const bf16x8*)(ar0 + kb);
        bf16x8 a1 = *(const bf16x8*)(ar1 + kb);
#pragma unroll
        for (int j = 0; j < 8; j++) {
            bf16x8 bv = *(const bf16x8*)&Bs[(j * 16 + fr) * 264 + kb];
            acc[0][j] = __builtin_amdgcn_mfma_f32_16x16x32_bf16(a0, bv, acc[0][j], 0, 0, 0);
            acc[1][j] = __builtin_amdgcn_mfma_f32_16x16x32_bf16(a1, bv, acc[1][j], 0, 0, 0);
        }
    }

#pragma unroll
    for (int g = 0; g < 2; g++) {
        const int row0 = rbase + g * 16 + (lane >> 4) * 4;
#pragma unroll
        for (int j = 0; j < 8; j++) {
            const int col = j * 16 + fr;
#pragma unroll
            for (int q = 0; q < 4; q++) {
                const int row = row0 + q;
                if (row < MTOT)
                    C[(size_t)row * DOUT + col] = f2b(acc[g][j][q]);
            }
        }
    }
}

// ---------------------------------------------------------------------------
// Fused aggregation + bias (+ReLU) + LayerNorm.  ONE LANE-GROUP PER NODE.
// (unchanged from the passing 227us version)
// ---------------------------------------------------------------------------
template <int D, bool RELU, typename OutT>
__global__ __launch_bounds__(256) void k_agg(const ushort* __restrict__ h,
                                             const int* __restrict__ rowptr,
                                             const int2* __restrict__ edges,
                                             const float* __restrict__ dinv,
                                             const float* __restrict__ bias,
                                             const float* __restrict__ gam,
                                             const float* __restrict__ bet,
                                             OutT* __restrict__ out) {
    constexpr int F = 8;               // features per lane (16B gathers)
    constexpr int GL = D / F;          // lanes per node group (32 / 16)
    constexpr int NPW = 64 / GL;       // nodes per wave (2 / 4)
    __shared__ int2 s_rec[4][64];      // per-wave record slots (2KB)
    const int tid = threadIdx.x;
    const int lane = tid & 63;
    const int wv = tid >> 6;
    const int grp = lane / GL;         // node slot within wave
    const int gl = lane & (GL - 1);    // lane within group
    const int fb = gl * F;             // feature base
    const int g = blockIdx.x & 7;      // graph -> XCD affinity
    const int n = (blockIdx.x >> 3) * (4 * NPW) + wv * NPW + grp;
    const ushort* hg = h + (size_t)g * NN * D;
    const int2* eg = edges + (size_t)g * EE;
    const int r0 = rowptr[g * (NN + 1) + n];
    const int r1 = rowptr[g * (NN + 1) + n + 1];
    const float dn = dinv[g * NN + n];
    int2* srw = &s_rec[wv][grp * GL];  // group's private slot region

    float acc[F];
#pragma unroll
    for (int i = 0; i < F; i++) acc[i] = 0.f;

    for (int base = r0; base < r1; base += GL) {
        const int c = min(GL, r1 - base);
        int2 rec;
        rec.x = 0;
        rec.y = 0;
        if (gl < c) rec = eg[base + gl];
        srw[gl] = rec;
        const int cpad = (c + 3) & ~3;
        for (int j = 0; j < cpad; j += 4) {
            const int4 ra = *(const int4*)&srw[j];      // records j, j+1
            const int4 rb = *(const int4*)&srw[j + 2];  // records j+2, j+3
            u16x8 v0 = *(const u16x8*)&hg[(size_t)ra.x * D + fb];
            u16x8 v1 = *(const u16x8*)&hg[(size_t)ra.z * D + fb];
            u16x8 v2 = *(const u16x8*)&hg[(size_t)rb.x * D + fb];
            u16x8 v3 = *(const u16x8*)&hg[(size_t)rb.z * D + fb];
            const float w0 = __int_as_float(ra.y);
            const float w1 = __int_as_float(ra.w);
            const float w2 = __int_as_float(rb.y);
            const float w3 = __int_as_float(rb.w);
#pragma unroll
            for (int i = 0; i < F; i++) acc[i] = fmaf(bf2f(v0[i]), w0, acc[i]);
#pragma unroll
            for (int i = 0; i < F; i++) acc[i] = fmaf(bf2f(v1[i]), w1, acc[i]);
#pragma unroll
            for (int i = 0; i < F; i++) acc[i] = fmaf(bf2f(v2[i]), w2, acc[i]);
#pragma unroll
            for (int i = 0; i < F; i++) acc[i] = fmaf(bf2f(v3[i]), w3, acc[i]);
        }
    }

    {
        const float ws = dn * dn;
        u16x8 v = *(const u16x8*)&hg[(size_t)n * D + fb];
#pragma unroll
        for (int i = 0; i < F; i++) {
            acc[i] = fmaf(bf2f(v[i]), ws, acc[i]);
            acc[i] += bias[fb + i];
            if (RELU) acc[i] = fmaxf(acc[i], 0.f);
        }
    }
    float s1 = 0.f, s2 = 0.f;
#pragma unroll
    for (int i = 0; i < F; i++) { s1 += acc[i]; s2 += acc[i] * acc[i]; }
#pragma unroll
    for (int o = GL / 2; o > 0; o >>= 1) {
        s1 += __shfl_xor(s1, o);
        s2 += __shfl_xor(s2, o);
    }
    const float mu = s1 / D;
    const float rs = rsqrtf(s2 / D - mu * mu + LN_EPS);

    if constexpr (sizeof(OutT) == 2) {
        u16x8 o;
#pragma unroll
        for (int i = 0; i < F; i++)
            o[i] = f2b((acc[i] - mu) * rs * gam[fb + i] + bet[fb + i]);
        *(u16x8*)&((ushort*)out)[((size_t)g * NN + n) * D + fb] = o;
    } else {
        float* op = &((float*)out)[((size_t)g * NN + n) * D + fb];
        float4 oa, ob;
        oa.x = (acc[0] - mu) * rs * gam[fb + 0] + bet[fb + 0];
        oa.y = (acc[1] - mu) * rs * gam[fb + 1] + bet[fb + 1];
        oa.z = (acc[2] - mu) * rs * gam[fb + 2] + bet[fb + 2];
        oa.w = (acc[3] - mu) * rs * gam[fb + 3] + bet[fb + 3];
        ob.x = (acc[4] - mu) * rs * gam[fb + 4] + bet[fb + 4];
        ob.y = (acc[5] - mu) * rs * gam[fb + 5] + bet[fb + 5];
        ob.z = (acc[6] - mu) * rs * gam[fb + 6] + bet[fb + 6];
        ob.w = (acc[7] - mu) * rs * gam[fb + 7] + bet[fb + 7];
        *(float4*)&op[0] = oa;
        *(float4*)&op[4] = ob;
    }
}

// ---------------------------------------------------------------------------
extern "C" void kernel_launch(void* const* d_in, const int* in_sizes, int n_in,
                              void* d_out, int out_size, void* d_ws, size_t ws_size,
                              hipStream_t stream) {
    const float* x   = (const float*)d_in[0];  // [G,N,300]
    const int*   ei  = (const int*)d_in[1];    // [G,2,E]
    const float* W1  = (const float*)d_in[2];  // [300,256]
    const float* b1  = (const float*)d_in[3];
    const float* g1  = (const float*)d_in[4];
    const float* be1 = (const float*)d_in[5];
    const float* W2  = (const float*)d_in[6];  // [256,128]
    const float* b2  = (const float*)d_in[7];
    const float* g2  = (const float*)d_in[8];
    const float* be2 = (const float*)d_in[9];
    float* out = (float*)d_out;                // [G,N,128]

    // workspace layout (all 16B-aligned)
    char* w = (char*)d_ws;
    ushort* w1t  = (ushort*)w;                        w += (size_t)DH * KP1 * 2;
    ushort* w2t  = (ushort*)w;                        w += (size_t)DOUT * DH * 2;
    ushort* h1b  = (ushort*)w;                        w += (size_t)MTOT * DH * 2;     // 41MB
    ushort* out1 = (ushort*)w;                        w += (size_t)MTOT * DH * 2;     // 41MB
    int*   cnt    = (int*)w;                          w += (size_t)GG * NN * 4;
    int*   rowptr = (int*)w;                          w += (size_t)GG * (NN + 1) * 4 + 224; // pad to 16B
    int*   slot   = (int*)w;                          w += (size_t)GG * EE * 4;       // 5.1MB
    float* dinv   = (float*)w;                        w += (size_t)GG * NN * 4;
    int2*  edges  = (int2*)w;                         /* G*E*8 = 10.2MB */
    ushort* h2b = h1b;

    // 1. util: zero cnt + cast W1/W2 (one launch)
    k_util<<<dim3((DH * KP1 + 255) / 256), dim3(256), 0, stream>>>(W1, W2, w1t, w2t, cnt);

    // 2. build CSR (atomic slot assign -> scan -> atomic-free fill w/ fat records)
    k_count<<<dim3((EE / 256) * GG), dim3(256), 0, stream>>>(ei, cnt, slot);
    k_scan<<<dim3(GG), dim3(256), 0, stream>>>(cnt, rowptr, dinv);
    k_fill<<<dim3((EE / 256) * GG), dim3(256), 0, stream>>>(ei, rowptr, slot, dinv, edges);

    // 3. h1 = bf16(x) @ W1  (B-resident LDS, barrier-free M-loop)
    k_gemm1<<<dim3(4, (MTOT + 255) / 256), dim3(512), 0, stream>>>(x, w1t, h1b);

    // 4. conv1 aggregate + bias + relu + LN -> out1 (bf16): 8 nodes/block
    k_agg<DH, true, ushort><<<dim3((NN / 8) * GG), dim3(256), 0, stream>>>(
        h1b, rowptr, edges, dinv, b1, g1, be1, out1);

    // 5. h2 = out1 @ W2  (B-resident LDS, barrier-free M-loop)
    k_gemm2<<<dim3((MTOT + 255) / 256), dim3(512), 0, stream>>>(out1, w2t, h2b);

    // 6. conv2 aggregate + bias + LN -> d_out (fp32): 16 nodes/block
    k_agg<DOUT, false, float><<<dim3((NN / 16) * GG), dim3(256), 0, stream>>>(
        h2b, rowptr, edges, dinv, b2, g2, be2, out);
}

// Round 6
// 235.100 us; speedup vs baseline: 1.1358x; 1.1358x over previous
//
#include <hip/hip_runtime.h>
#include <hip/hip_bf16.h>

// Problem constants (from reference)
#define GG   8
#define NN   10000
#define EE   160000       // = 625 * 256 exactly
#define DIN  300
#define KP1  320          // DIN padded to mult of 32
#define DH   256
#define DOUT 128
#define MTOT 80000        // G*N rows = 625 * 128 exactly
#define LN_EPS 1e-5f

typedef short bf16x8 __attribute__((ext_vector_type(8)));
typedef float f32x4  __attribute__((ext_vector_type(4)));
typedef ushort u16x8 __attribute__((ext_vector_type(8)));

__device__ inline float bf2f(ushort u) {
    union { unsigned int i; float f; } x;
    x.i = ((unsigned int)u) << 16;
    return x.f;
}
__device__ inline ushort f2b(float f) {
    union { float f; unsigned int u; } x;
    x.f = f;
    unsigned int u = x.u;
    return (ushort)((u + 0x7fffu + ((u >> 16) & 1u)) >> 16);  // RNE (finite values)
}
__device__ inline short bcvt(float f) {
    __hip_bfloat16 h = __float2bfloat16(f);   // RNE; compiler emits v_cvt
    return *reinterpret_cast<short*>(&h);
}

// ---------------------------------------------------------------------------
// k_util: zero cnt + cast W1 -> w1t [256][320] + cast W2 -> w2t [128][256]
// ---------------------------------------------------------------------------
__global__ __launch_bounds__(256) void k_util(const float* __restrict__ W1,
                                              const float* __restrict__ W2,
                                              ushort* __restrict__ w1t,
                                              ushort* __restrict__ w2t,
                                              int* __restrict__ cnt) {
    int i = blockIdx.x * blockDim.x + threadIdx.x;
    if (i < GG * NN) cnt[i] = 0;
    if (i < DH * KP1) {
        int n = i / KP1, k = i % KP1;
        w1t[i] = (k < DIN) ? f2b(W1[(size_t)k * DH + n]) : 0;
    }
    if (i < DOUT * DH) {
        int n = i / DH, k = i % DH;
        w2t[i] = f2b(W2[(size_t)k * DOUT + n]);
    }
}

// ---------------------------------------------------------------------------
// CSR build kernels
// ---------------------------------------------------------------------------
__global__ __launch_bounds__(256) void k_count(const int* __restrict__ ei,
                                               int* __restrict__ cnt,
                                               int* __restrict__ slot) {
    int bid = blockIdx.x;
    int g = bid & 7;
    int e = (bid >> 3) * 256 + threadIdx.x;       // e < EE exactly
    int dst = ei[(size_t)g * 2 * EE + EE + e];
    slot[(size_t)g * EE + e] = atomicAdd(&cnt[g * NN + dst], 1);
}

__global__ void k_scan(const int* __restrict__ cnt, int* __restrict__ rowptr,
                       float* __restrict__ dinv) {
    int g = blockIdx.x;
    int t = threadIdx.x;                // 256 threads
    const int per = (NN + 255) / 256;   // 40
    __shared__ int sums[256];
    __shared__ int offs[257];
    int base = t * per;
    int s = 0;
    for (int i = 0; i < per; i++) {
        int n = base + i;
        if (n < NN) s += cnt[g * NN + n];
    }
    sums[t] = s;
    __syncthreads();
    if (t == 0) {
        int acc = 0;
        for (int i = 0; i < 256; i++) { offs[i] = acc; acc += sums[i]; }
        offs[256] = acc;
    }
    __syncthreads();
    int run = offs[t];
    for (int i = 0; i < per; i++) {
        int n = base + i;
        if (n < NN) {
            int c = cnt[g * NN + n];
            rowptr[g * (NN + 1) + n] = run;
            dinv[g * NN + n] = 1.0f / sqrtf(1.0f + (float)c);
            run += c;
        }
    }
    if (t == 255) rowptr[g * (NN + 1) + NN] = offs[256];
}

__global__ __launch_bounds__(256) void k_fill(const int* __restrict__ ei,
                                              const int* __restrict__ rowptr,
                                              const int* __restrict__ slot,
                                              const float* __restrict__ dinv,
                                              int2* __restrict__ edges) {
    int bid = blockIdx.x;
    int g = bid & 7;
    int e = (bid >> 3) * 256 + threadIdx.x;
    int src = ei[(size_t)g * 2 * EE + e];
    int dst = ei[(size_t)g * 2 * EE + EE + e];
    int pos = rowptr[g * (NN + 1) + dst] + slot[(size_t)g * EE + e];
    float coef = dinv[g * NN + src] * dinv[g * NN + dst];
    int2 rec;
    rec.x = src;
    rec.y = __float_as_int(coef);
    edges[(size_t)g * EE + pos] = rec;
}

// ---------------------------------------------------------------------------
// GEMM1:  C[80000,256] = bf16(x[80000,300]) @ W1  (fused fp32->bf16 cast)
// A-READ-ONCE structure (fixes R5's 4x A over-fetch, FETCH 217MB->~52MB):
// grid 625 x {128 rows, 512 thr = 8 waves x 16 rows}.  Each lane holds its
// row's ENTIRE K-slice in regs (a[10] bf16x8, cvt'd once).  B (w1t) is
// processed in 4 column-quarters, DOUBLE-BUFFERED in LDS with the
// m99/m100-proven pattern: stage(q+1,buf^1); compute(q,buf); __syncthreads().
// Full __syncthreads semantics (compiler fence + vm/lgkm drain) — no inline
// asm, no counted vmcnt (both R1/R2 race sources).  4 barriers per block.
// LDS: 2 x 64x320 ush = 80 KB exactly -> 2 blocks/CU.  Chunk-XOR layout
// (c&7)^(row&7), stride 320 (no pad): balanced 8 lanes/16B-slot on b128
// reads (the wave64 optimum) at zero LDS overhead.
// K-tail: A loads clamp to col 296 (f32x4-granular); displaced slots k>=300
// multiply w1t's zero rows.  No M-tail (625*128 = 80000).
// ---------------------------------------------------------------------------
__global__ __launch_bounds__(512) void k_gemm1(const float* __restrict__ x,
                                               const ushort* __restrict__ Bt,
                                               ushort* __restrict__ C) {
    __shared__ ushort Bs[2][64 * 320];   // 2 x 40 KB
    const int tid = threadIdx.x;
    const int lane = tid & 63;
    const int w = tid >> 6;              // 0..7
    const int fr = lane & 15;            // row within wave tile
    const int hi = lane >> 4;            // 0..3, k-subchunk
    const int row = blockIdx.x * 128 + w * 16 + fr;
    const float* xr = x + (size_t)row * DIN;

    // ---- A: whole K-slice of this lane's row -> regs (cvt once) ----
    bf16x8 a[10];
#pragma unroll
    for (int kk = 0; kk < 10; kk++) {
        const int kb = kk * 32 + hi * 8;
        f32x4 p = *(const f32x4*)(xr + min(kb, DIN - 4));
        f32x4 q = *(const f32x4*)(xr + min(kb + 4, DIN - 4));
        a[kk][0] = bcvt(p[0]); a[kk][1] = bcvt(p[1]);
        a[kk][2] = bcvt(p[2]); a[kk][3] = bcvt(p[3]);
        a[kk][4] = bcvt(q[0]); a[kk][5] = bcvt(q[1]);
        a[kk][6] = bcvt(q[2]); a[kk][7] = bcvt(q[3]);
    }

    // stage one 64-col quarter of B: 64 rows x 40 chunks (u16x8), XOR'd dest
    auto stageQ = [&](int q, int buf) {
        for (int idx = tid; idx < 64 * 40; idx += 512) {
            const int r = idx / 40;
            const int c = idx - r * 40;
            const int cs = (c & ~7) | ((c & 7) ^ (r & 7));
            *(u16x8*)&Bs[buf][r * 320 + cs * 8] =
                *(const u16x8*)&Bt[(size_t)(q * 64 + r) * KP1 + c * 8];
        }
    };

    f32x4 acc[4][4];
#pragma unroll
    for (int q = 0; q < 4; q++)
#pragma unroll
        for (int j = 0; j < 4; j++) acc[q][j] = (f32x4){0.f, 0.f, 0.f, 0.f};

    stageQ(0, 0);
    __syncthreads();
#pragma unroll
    for (int q = 0; q < 4; q++) {
        const int buf = q & 1;
        if (q < 3) stageQ(q + 1, buf ^ 1);
#pragma unroll
        for (int kk = 0; kk < 10; kk++) {
            const int cb = kk * 4 + hi;            // global k-chunk index
#pragma unroll
            for (int j = 0; j < 4; j++) {
                const int r = j * 16 + fr;
                const int cs = (cb & ~7) | ((cb & 7) ^ (r & 7));
                bf16x8 bv = *(const bf16x8*)&Bs[buf][r * 320 + cs * 8];
                acc[q][j] = __builtin_amdgcn_mfma_f32_16x16x32_bf16(a[kk], bv,
                                                                    acc[q][j], 0, 0, 0);
            }
        }
        if (q < 3) __syncthreads();
    }

    // epilogue: C/D layout col=lane&15, row=(lane>>4)*4+qq
    const int row0 = blockIdx.x * 128 + w * 16 + hi * 4;
#pragma unroll
    for (int q = 0; q < 4; q++)
#pragma unroll
        for (int j = 0; j < 4; j++) {
            const int col = q * 64 + j * 16 + fr;
#pragma unroll
            for (int qq = 0; qq < 4; qq++)
                C[(size_t)(row0 + qq) * DH + col] = f2b(acc[q][j][qq]);
        }
}

// ---------------------------------------------------------------------------
// GEMM2: C[80000,128] = A[80000,256](bf16) @ w2t[128,256]^T
// Whole B fits LDS (128x256 ush = 64 KB -> 2 blocks/CU).  Stage once,
// ONE barrier, then pure reg+LDS compute (64 MFMAs/wave), write C.
// Same chunk-XOR layout (stride 256: slot = cs&7, balanced-8).
// grid 625 x {128 rows, 512 thr = 8 waves x 16 rows}.  No tails.
// ---------------------------------------------------------------------------
__global__ __launch_bounds__(512) void k_gemm2(const ushort* __restrict__ A,
                                               const ushort* __restrict__ Bt,
                                               ushort* __restrict__ C) {
    __shared__ ushort Bs[128 * 256];     // 64 KB
    const int tid = threadIdx.x;
    const int lane = tid & 63;
    const int w = tid >> 6;
    const int fr = lane & 15;
    const int hi = lane >> 4;
    const int row = blockIdx.x * 128 + w * 16 + fr;
    const ushort* ar = A + (size_t)row * DH;

    // A K-slice -> regs
    bf16x8 a[8];
#pragma unroll
    for (int kk = 0; kk < 8; kk++)
        a[kk] = *(const bf16x8*)(ar + kk * 32 + hi * 8);

    // stage whole B: 128 rows x 32 chunks, XOR'd dest
    for (int idx = tid; idx < 128 * 32; idx += 512) {
        const int r = idx >> 5;
        const int c = idx & 31;
        const int cs = (c & ~7) | ((c & 7) ^ (r & 7));
        *(u16x8*)&Bs[r * 256 + cs * 8] =
            *(const u16x8*)&Bt[(size_t)r * DH + c * 8];
    }
    __syncthreads();

    f32x4 acc[8];
#pragma unroll
    for (int j = 0; j < 8; j++) acc[j] = (f32x4){0.f, 0.f, 0.f, 0.f};

#pragma unroll
    for (int kk = 0; kk < 8; kk++) {
        const int cb = kk * 4 + hi;
#pragma unroll
        for (int j = 0; j < 8; j++) {
            const int r = j * 16 + fr;
            const int cs = (cb & ~7) | ((cb & 7) ^ (r & 7));
            bf16x8 bv = *(const bf16x8*)&Bs[r * 256 + cs * 8];
            acc[j] = __builtin_amdgcn_mfma_f32_16x16x32_bf16(a[kk], bv,
                                                             acc[j], 0, 0, 0);
        }
    }

    const int row0 = blockIdx.x * 128 + w * 16 + hi * 4;
#pragma unroll
    for (int j = 0; j < 8; j++) {
        const int col = j * 16 + fr;
#pragma unroll
        for (int qq = 0; qq < 4; qq++)
            C[(size_t)(row0 + qq) * DOUT + col] = f2b(acc[j][qq]);
    }
}

// ---------------------------------------------------------------------------
// Fused aggregation + bias (+ReLU) + LayerNorm.  ONE LANE-GROUP PER NODE.
// (unchanged from the passing 227us version)
// ---------------------------------------------------------------------------
template <int D, bool RELU, typename OutT>
__global__ __launch_bounds__(256) void k_agg(const ushort* __restrict__ h,
                                             const int* __restrict__ rowptr,
                                             const int2* __restrict__ edges,
                                             const float* __restrict__ dinv,
                                             const float* __restrict__ bias,
                                             const float* __restrict__ gam,
                                             const float* __restrict__ bet,
                                             OutT* __restrict__ out) {
    constexpr int F = 8;               // features per lane (16B gathers)
    constexpr int GL = D / F;          // lanes per node group (32 / 16)
    constexpr int NPW = 64 / GL;       // nodes per wave (2 / 4)
    __shared__ int2 s_rec[4][64];      // per-wave record slots (2KB)
    const int tid = threadIdx.x;
    const int lane = tid & 63;
    const int wv = tid >> 6;
    const int grp = lane / GL;         // node slot within wave
    const int gl = lane & (GL - 1);    // lane within group
    const int fb = gl * F;             // feature base
    const int g = blockIdx.x & 7;      // graph -> XCD affinity
    const int n = (blockIdx.x >> 3) * (4 * NPW) + wv * NPW + grp;
    const ushort* hg = h + (size_t)g * NN * D;
    const int2* eg = edges + (size_t)g * EE;
    const int r0 = rowptr[g * (NN + 1) + n];
    const int r1 = rowptr[g * (NN + 1) + n + 1];
    const float dn = dinv[g * NN + n];
    int2* srw = &s_rec[wv][grp * GL];  // group's private slot region

    float acc[F];
#pragma unroll
    for (int i = 0; i < F; i++) acc[i] = 0.f;

    for (int base = r0; base < r1; base += GL) {
        const int c = min(GL, r1 - base);
        int2 rec;
        rec.x = 0;
        rec.y = 0;
        if (gl < c) rec = eg[base + gl];
        srw[gl] = rec;
        const int cpad = (c + 3) & ~3;
        for (int j = 0; j < cpad; j += 4) {
            const int4 ra = *(const int4*)&srw[j];      // records j, j+1
            const int4 rb = *(const int4*)&srw[j + 2];  // records j+2, j+3
            u16x8 v0 = *(const u16x8*)&hg[(size_t)ra.x * D + fb];
            u16x8 v1 = *(const u16x8*)&hg[(size_t)ra.z * D + fb];
            u16x8 v2 = *(const u16x8*)&hg[(size_t)rb.x * D + fb];
            u16x8 v3 = *(const u16x8*)&hg[(size_t)rb.z * D + fb];
            const float w0 = __int_as_float(ra.y);
            const float w1 = __int_as_float(ra.w);
            const float w2 = __int_as_float(rb.y);
            const float w3 = __int_as_float(rb.w);
#pragma unroll
            for (int i = 0; i < F; i++) acc[i] = fmaf(bf2f(v0[i]), w0, acc[i]);
#pragma unroll
            for (int i = 0; i < F; i++) acc[i] = fmaf(bf2f(v1[i]), w1, acc[i]);
#pragma unroll
            for (int i = 0; i < F; i++) acc[i] = fmaf(bf2f(v2[i]), w2, acc[i]);
#pragma unroll
            for (int i = 0; i < F; i++) acc[i] = fmaf(bf2f(v3[i]), w3, acc[i]);
        }
    }

    {
        const float ws = dn * dn;
        u16x8 v = *(const u16x8*)&hg[(size_t)n * D + fb];
#pragma unroll
        for (int i = 0; i < F; i++) {
            acc[i] = fmaf(bf2f(v[i]), ws, acc[i]);
            acc[i] += bias[fb + i];
            if (RELU) acc[i] = fmaxf(acc[i], 0.f);
        }
    }
    float s1 = 0.f, s2 = 0.f;
#pragma unroll
    for (int i = 0; i < F; i++) { s1 += acc[i]; s2 += acc[i] * acc[i]; }
#pragma unroll
    for (int o = GL / 2; o > 0; o >>= 1) {
        s1 += __shfl_xor(s1, o);
        s2 += __shfl_xor(s2, o);
    }
    const float mu = s1 / D;
    const float rs = rsqrtf(s2 / D - mu * mu + LN_EPS);

    if constexpr (sizeof(OutT) == 2) {
        u16x8 o;
#pragma unroll
        for (int i = 0; i < F; i++)
            o[i] = f2b((acc[i] - mu) * rs * gam[fb + i] + bet[fb + i]);
        *(u16x8*)&((ushort*)out)[((size_t)g * NN + n) * D + fb] = o;
    } else {
        float* op = &((float*)out)[((size_t)g * NN + n) * D + fb];
        float4 oa, ob;
        oa.x = (acc[0] - mu) * rs * gam[fb + 0] + bet[fb + 0];
        oa.y = (acc[1] - mu) * rs * gam[fb + 1] + bet[fb + 1];
        oa.z = (acc[2] - mu) * rs * gam[fb + 2] + bet[fb + 2];
        oa.w = (acc[3] - mu) * rs * gam[fb + 3] + bet[fb + 3];
        ob.x = (acc[4] - mu) * rs * gam[fb + 4] + bet[fb + 4];
        ob.y = (acc[5] - mu) * rs * gam[fb + 5] + bet[fb + 5];
        ob.z = (acc[6] - mu) * rs * gam[fb + 6] + bet[fb + 6];
        ob.w = (acc[7] - mu) * rs * gam[fb + 7] + bet[fb + 7];
        *(float4*)&op[0] = oa;
        *(float4*)&op[4] = ob;
    }
}

// ---------------------------------------------------------------------------
extern "C" void kernel_launch(void* const* d_in, const int* in_sizes, int n_in,
                              void* d_out, int out_size, void* d_ws, size_t ws_size,
                              hipStream_t stream) {
    const float* x   = (const float*)d_in[0];  // [G,N,300]
    const int*   ei  = (const int*)d_in[1];    // [G,2,E]
    const float* W1  = (const float*)d_in[2];  // [300,256]
    const float* b1  = (const float*)d_in[3];
    const float* g1  = (const float*)d_in[4];
    const float* be1 = (const float*)d_in[5];
    const float* W2  = (const float*)d_in[6];  // [256,128]
    const float* b2  = (const float*)d_in[7];
    const float* g2  = (const float*)d_in[8];
    const float* be2 = (const float*)d_in[9];
    float* out = (float*)d_out;                // [G,N,128]

    // workspace layout (all 16B-aligned)
    char* w = (char*)d_ws;
    ushort* w1t  = (ushort*)w;                        w += (size_t)DH * KP1 * 2;
    ushort* w2t  = (ushort*)w;                        w += (size_t)DOUT * DH * 2;
    ushort* h1b  = (ushort*)w;                        w += (size_t)MTOT * DH * 2;     // 41MB
    ushort* out1 = (ushort*)w;                        w += (size_t)MTOT * DH * 2;     // 41MB
    int*   cnt    = (int*)w;                          w += (size_t)GG * NN * 4;
    int*   rowptr = (int*)w;                          w += (size_t)GG * (NN + 1) * 4 + 224; // pad to 16B
    int*   slot   = (int*)w;                          w += (size_t)GG * EE * 4;       // 5.1MB
    float* dinv   = (float*)w;                        w += (size_t)GG * NN * 4;
    int2*  edges  = (int2*)w;                         /* G*E*8 = 10.2MB */
    ushort* h2b = h1b;

    // 1. util: zero cnt + cast W1/W2 (one launch)
    k_util<<<dim3((DH * KP1 + 255) / 256), dim3(256), 0, stream>>>(W1, W2, w1t, w2t, cnt);

    // 2. build CSR (atomic slot assign -> scan -> atomic-free fill w/ fat records)
    k_count<<<dim3((EE / 256) * GG), dim3(256), 0, stream>>>(ei, cnt, slot);
    k_scan<<<dim3(GG), dim3(256), 0, stream>>>(cnt, rowptr, dinv);
    k_fill<<<dim3((EE / 256) * GG), dim3(256), 0, stream>>>(ei, rowptr, slot, dinv, edges);

    // 3. h1 = bf16(x) @ W1  (A-read-once, B quarter-dbuf LDS)
    k_gemm1<<<dim3(MTOT / 128), dim3(512), 0, stream>>>(x, w1t, h1b);

    // 4. conv1 aggregate + bias + relu + LN -> out1 (bf16): 8 nodes/block
    k_agg<DH, true, ushort><<<dim3((NN / 8) * GG), dim3(256), 0, stream>>>(
        h1b, rowptr, edges, dinv, b1, g1, be1, out1);

    // 5. h2 = out1 @ W2  (B fully LDS-resident, single barrier)
    k_gemm2<<<dim3(MTOT / 128), dim3(512), 0, stream>>>(out1, w2t, h2b);

    // 6. conv2 aggregate + bias + LN -> d_out (fp32): 16 nodes/block
    k_agg<DOUT, false, float><<<dim3((NN / 16) * GG), dim3(256), 0, stream>>>(
        h2b, rowptr, edges, dinv, b2, g2, be2, out);
}